// Round 12
// baseline (243.540 us; speedup 1.0000x reference)
//
#include <hip/hip_runtime.h>

#define NN 20000
#define EE 320000
#define CAP 64           // slab slots per node (in-degree ~ Poisson(16))
#define SVC 72           // per-wave edge capacity (CAP + ovf slack + self)
#define OVCAP 8192
#define EBLK 313         // edge blocks: ceil(320000/1024)
#define POISON64 0xAAAAAAAAAAAAAAAAull
#define POISON32 0xAAAAAAAAu

// consts layout (float offsets)
#define WZ_O 0
#define BZ_O 512
#define WH_O 576
#define BH_O 1088
#define OWT_O 1152       // transposed+padded out weights: [p][68] (k<64 valid)
#define OB_O 1968
#define PR_O 1980
#define NCONST 1992

__device__ __forceinline__ float b2f(unsigned short h) {
  union { unsigned int u; float f; } v; v.u = ((unsigned int)h) << 16; return v.f;
}
__device__ __forceinline__ unsigned short f2b(float f) {
  union { unsigned int u; float f; } v; v.f = f;
  unsigned int u = v.u;
  unsigned int r = (u + 0x7fffu + ((u >> 16) & 1u)) >> 16;  // RNE
  return (unsigned short)r;
}
__device__ __forceinline__ float ldw(const void* p, int i, int isbf) {
  return isbf ? b2f(((const unsigned short*)p)[i]) : ((const float*)p)[i];
}
__device__ __forceinline__ void upk(unsigned int w, float& x0, float& x1) {
  union { unsigned int u; float f; } lo, hi;
  lo.u = w << 16; hi.u = w & 0xffff0000u;
  x0 = lo.f; x1 = hi.f;
}
// poison-aware decode: 0xAA.. pattern (never a legal value: count=0xAAAAAAAA) -> 0
__device__ __forceinline__ unsigned long long dcfix(unsigned long long dc) {
  return (dc == POISON64) ? 0ull : dc;
}
__device__ __forceinline__ float degf(unsigned long long dc) {
  return (float)(unsigned int)dc * (1.0f / 1048576.0f);
}

// 1) k_append: blocks 0..EBLK-1 process 4 edges/thread. No pre-zero needed:
//    the first edge for a node CASes the 0xAA poison to its initial packed value.
//    Block EBLK (concurrent) computes fused weights into consts.
__global__ void __launch_bounds__(256) k_append(
    const void* __restrict__ ei, const void* __restrict__ ea,
    unsigned long long* __restrict__ degcnt,
    unsigned int* __restrict__ slab,
    unsigned int* __restrict__ ovf_cnt, int* __restrict__ ovf_dst,
    unsigned int* __restrict__ ovf_pack, float* __restrict__ consts,
    const void* czw, const void* czb, const void* chw, const void* chb,
    const void* lzw, const void* lzb, const void* lhw, const void* lhb,
    const void* att, const void* ow, const void* ob) {
  __shared__ int sfl[2];
  const int tid = threadIdx.x;
  if (tid < 64) {
    // edge_attr in (0,1): packed-bf16 words have sign bits 15/31==0; f32 random bit15
    unsigned long long b1 = __ballot((((const unsigned int*)ea)[tid] >> 15) & 1u);
    // edge_index < 20000: int64 arrays have all odd 32-bit words == 0
    unsigned long long b2 = __ballot(((const unsigned int*)ei)[2 * tid + 1] != 0u);
    if (tid == 0) {
      sfl[0] = (b1 == 0ull) ? 1 : 0;   // 1 = floats are bf16
      sfl[1] = (b2 == 0ull) ? 1 : 0;   // 1 = indices are int64
    }
  }
  __syncthreads();
  const int isbf = sfl[0], is64 = sfl[1];

  if (blockIdx.x == EBLK) {
    // ---- weight prep block (concurrent with edge blocks) ----
    for (int idx = tid; idx < 512; idx += 256) {
      int f = idx >> 6, k = idx & 63;
      float sz = 0.f, sh = 0.f;
      for (int h = 0; h < 64; ++h) {
        sz += ldw(czw, f * 64 + h, isbf) * ldw(lzw, h * 64 + k, isbf);
        sh += ldw(chw, f * 64 + h, isbf) * ldw(lhw, h * 64 + k, isbf);
      }
      consts[WZ_O + idx] = sz; consts[WH_O + idx] = sh;
    }
    for (int idx = tid; idx < 64; idx += 256) {
      float sz = ldw(lzb, idx, isbf), sh = ldw(lhb, idx, isbf);
      for (int h = 0; h < 64; ++h) {
        sz += ldw(czb, h, isbf) * ldw(lzw, h * 64 + idx, isbf);
        sh += ldw(chb, h, isbf) * ldw(lhw, h * 64 + idx, isbf);
      }
      consts[BZ_O + idx] = sz; consts[BH_O + idx] = sh;
    }
    for (int idx = tid; idx < 816; idx += 256) {    // out weights [p][k], rows padded to 68
      int p = idx / 68, kk = idx % 68;
      consts[OWT_O + idx] = (kk < 64) ? ldw(ow, kk * 12 + p, isbf) : 0.f;
    }
    if (tid < 12) consts[OB_O + tid] = ldw(ob, tid, isbf);
    if (tid == 0) {
      float a[12]; float m = -1e30f;
      for (int p = 0; p < 12; ++p) { a[p] = ldw(att, p, isbf); m = fmaxf(m, a[p]); }
      float ssum = 0.f;
      for (int p = 0; p < 12; ++p) { a[p] = __expf(a[p] - m); ssum += a[p]; }
      for (int p = 0; p < 12; ++p) consts[PR_O + p] = a[p] / ssum;
    }
    return;
  }

  // ---- edge blocks: 4 edges per thread, independent chains ----
  const int e0 = blockIdx.x * 1024 + tid;
#pragma unroll
  for (int u = 0; u < 4; ++u) {
    int e = e0 + 256 * u;
    if (e >= EE) continue;
    int r, c;
    if (is64) {
      r = (int)((const unsigned int*)ei)[2 * e];
      c = (int)((const unsigned int*)ei)[2 * (EE + e)];
    } else {
      r = ((const int*)ei)[e];
      c = ((const int*)ei)[EE + e];
    }
    unsigned short wb;
    float w;
    if (isbf) { wb = ((const unsigned short*)ea)[e]; w = b2f(wb); }
    else      { w = ((const float*)ea)[e]; wb = f2b(w); }
    unsigned long long pk = (1ull << 32) |
        (unsigned long long)(unsigned int)__float2int_rn(w * 1048576.0f);
    // poison-tolerant init: first writer CASes poison -> pk (pos 0)
    unsigned long long old = atomicCAS(&degcnt[c], POISON64, pk);
    int pos;
    if (old == POISON64) {
      pos = 0;
    } else {
      old = atomicAdd(&degcnt[c], pk);   // value is valid once any CAS succeeded
      pos = (int)(old >> 32);
    }
    unsigned int packed = ((unsigned int)wb << 16) | (unsigned int)r;
    if (pos < CAP) {
      slab[c * CAP + pos] = packed;
    } else {
      unsigned int oldc = atomicCAS(ovf_cnt, POISON32, 1u);
      int oi = (oldc == POISON32) ? 0 : (int)atomicAdd(ovf_cnt, 1u);
      if (oi < OVCAP) { ovf_dst[oi] = c; ovf_pack[oi] = packed; }
    }
  }
}

#define ACC8(u, v)                                           \
  { float x0, x1;                                            \
    upk((u).x, x0, x1); a[0] += (v) * x0; a[1] += (v) * x1;  \
    upk((u).y, x0, x1); a[2] += (v) * x0; a[3] += (v) * x1;  \
    upk((u).z, x0, x1); a[4] += (v) * x0; a[5] += (v) * x1;  \
    upk((u).w, x0, x1); a[6] += (v) * x0; a[7] += (v) * x1; }

#define ACCF8(u0, u1, v)                                                       \
  { a[0] += (v) * (u0).x; a[1] += (v) * (u0).y; a[2] += (v) * (u0).z;          \
    a[3] += (v) * (u0).w; a[4] += (v) * (u1).x; a[5] += (v) * (u1).y;          \
    a[6] += (v) * (u1).z; a[7] += (v) * (u1).w; }

// 2) barrier-free wave-per-node (round-8/10 structure): 4 waves/block.
//    Dtype flags re-derived locally (no global flags dependency).
__global__ void __launch_bounds__(256) k_node(
    const void* __restrict__ x, const void* __restrict__ ei,
    const void* __restrict__ ea,
    const unsigned long long* __restrict__ degcnt,
    const unsigned int* __restrict__ slab,
    const unsigned int* __restrict__ ovf_cnt, const int* __restrict__ ovf_dst,
    const unsigned int* __restrict__ ovf_pack,
    const float* __restrict__ consts,
    void* __restrict__ out) {
  __shared__ __align__(16) float sow[840];        // owT 816 | ob 12 | pr 12
  __shared__ __align__(16) int2  sv[4 * SVC];     // per-wave edges {soff, v-bits}
  __shared__ __align__(16) float accT[4 * 384];   // per-wave [b][p][f]
  __shared__ __align__(16) float hw[4 * 272];     // per-wave [b][68]
  __shared__ int swcnt[4];
  __shared__ int sfl[1];

  const int tid  = threadIdx.x;
  const int w    = tid >> 6;
  const int lane = tid & 63;
  const int n    = blockIdx.x * 4 + w;

  if (tid < 64) {
    unsigned long long b1 = __ballot((((const unsigned int*)ea)[tid] >> 15) & 1u);
    if (tid == 0) sfl[0] = (b1 == 0ull) ? 1 : 0;
  }
  for (int i = tid; i < 840; i += 256) sow[i] = consts[OWT_O + i];
  float wz[8], wh[8];
#pragma unroll
  for (int f = 0; f < 8; ++f) {
    wz[f] = consts[WZ_O + f * 64 + lane];
    wh[f] = consts[WH_O + f * 64 + lane];
  }
  const float bz = consts[BZ_O + lane], bh = consts[BH_O + lane];
  __syncthreads();   // sow + sfl ready (only block barrier)
  const int isbf = sfl[0];

  // --- stage this wave's edges into its LDS slab ---
  unsigned long long dcn = dcfix(degcnt[n]);
  int cnt = (int)(dcn >> 32);
  int base = cnt < CAP ? cnt : CAP;
  const float dn = rsqrtf(degf(dcn) + 1.0f);
  int2* svw = &sv[w * SVC];
  if (lane == 0) swcnt[w] = base;
  if (lane < base) {
    unsigned int pk = slab[n * CAP + lane];
    int s = (int)(pk & 0xffffu);
    float v = b2f((unsigned short)(pk >> 16)) *
              rsqrtf(degf(dcfix(degcnt[s])) + 1.0f);
    svw[lane] = make_int2(s * 96, __float_as_int(v));
  }
  int m0 = base;
  {
    unsigned int ovRaw = *ovf_cnt;
    int ov = (ovRaw == POISON32) ? 0 : (int)ovRaw;   // expected 0
    if (ov > 0) {
      if (ov > OVCAP) ov = OVCAP;
      for (int i = lane; i < ov; i += 64) {
        if (ovf_dst[i] == n) {
          int idx = atomicAdd(&swcnt[w], 1);
          if (idx < SVC - 1) {
            unsigned int pk = ovf_pack[i];
            int s = (int)(pk & 0xffffu);
            float v = b2f((unsigned short)(pk >> 16)) *
                      rsqrtf(degf(dcfix(degcnt[s])) + 1.0f);
            svw[idx] = make_int2(s * 96, __float_as_int(v));
          }
        }
      }
      __builtin_amdgcn_wave_barrier();
      m0 = swcnt[w];
      if (m0 > SVC - 1) m0 = SVC - 1;
    }
  }
  if (lane == 0) svw[m0] = make_int2(n * 96, __float_as_int(dn));  // self loop
  const int m1 = m0 + 1;
  __builtin_amdgcn_wave_barrier();

  // --- gather: lanes 0..47, lane owns 8 payload elems; 2-wide pipelined loads ---
  float a[8];
#pragma unroll
  for (int t = 0; t < 8; ++t) a[t] = 0.f;
  if (lane < 48) {
    const long xbase = (long)(lane / 12) * (NN * 96) + 8 * (lane % 12);
    if (isbf) {
      const unsigned short* xb = (const unsigned short*)x;
      int j = 0;
      for (; j + 1 < m1; j += 2) {
        int2 e0 = svw[j], e1 = svw[j + 1];
        uint4 u0 = *(const uint4*)(xb + xbase + e0.x);
        uint4 u1 = *(const uint4*)(xb + xbase + e1.x);
        float v0 = __int_as_float(e0.y), v1 = __int_as_float(e1.y);
        ACC8(u0, v0); ACC8(u1, v1);
      }
      if (j < m1) {
        int2 e0 = svw[j];
        uint4 u0 = *(const uint4*)(xb + xbase + e0.x);
        float v0 = __int_as_float(e0.y);
        ACC8(u0, v0);
      }
    } else {
      const float* xf = (const float*)x;
      int j = 0;
      for (; j + 1 < m1; j += 2) {
        int2 e0 = svw[j], e1 = svw[j + 1];
        const float4* p0 = (const float4*)(xf + xbase + e0.x);
        const float4* p1 = (const float4*)(xf + xbase + e1.x);
        float4 u00 = p0[0], u01 = p0[1], u10 = p1[0], u11 = p1[1];
        float v0 = __int_as_float(e0.y), v1 = __int_as_float(e1.y);
        ACCF8(u00, u01, v0); ACCF8(u10, u11, v1);
      }
      if (j < m1) {
        int2 e0 = svw[j];
        const float4* p0 = (const float4*)(xf + xbase + e0.x);
        float4 u00 = p0[0], u01 = p0[1];
        float v0 = __int_as_float(e0.y);
        ACCF8(u00, u01, v0);
      }
    }
    // scatter-transpose into accT[b][p][f], scaled by dn
    float* accTw = &accT[w * 384];
    const int bq = (lane / 12) * 96, oc = 8 * (lane % 12);
#pragma unroll
    for (int t = 0; t < 8; ++t) {
      int eib = oc + t;
      int f = eib / 12, p = eib % 12;
      accTw[bq + p * 8 + f] = dn * a[t];
    }
  }
  __builtin_amdgcn_wave_barrier();

  // --- gates: lane = hidden index k; all 48 (b,p) pairs; h accumulated per b ---
  {
    const float* accTw = &accT[w * 384];
    float* hww = &hw[w * 272];
#pragma unroll
    for (int b = 0; b < 4; ++b) {
      float hbl = 0.f;
#pragma unroll
      for (int p = 0; p < 12; ++p) {
        const float4* A = (const float4*)&accTw[b * 96 + p * 8];
        float4 A0 = A[0], A1 = A[1];
        float za = bz + A0.x * wz[0] + A0.y * wz[1] + A0.z * wz[2] + A0.w * wz[3]
                      + A1.x * wz[4] + A1.y * wz[5] + A1.z * wz[6] + A1.w * wz[7];
        float ta = bh + A0.x * wh[0] + A0.y * wh[1] + A0.z * wh[2] + A0.w * wh[3]
                      + A1.x * wh[4] + A1.y * wh[5] + A1.z * wh[6] + A1.w * wh[7];
        // (1 - sigmoid(za)) * tanh(ta) = (eh-1)/((1+ea)(1+eh)), ea=e^za, eh=e^{2ta}
        float ea2 = __expf(za);
        float eh = __expf(2.0f * fminf(ta, 40.0f));
        hbl += sow[828 + p] * (eh - 1.0f) *
               __builtin_amdgcn_rcpf((1.0f + ea2) * (1.0f + eh));
      }
      hww[b * 68 + lane] = fmaxf(hbl, 0.f);   // relu
    }
  }
  __builtin_amdgcn_wave_barrier();

  // --- out projection: lane t<48 -> (b,p); vectorized b128 reads ---
  if (lane < 48) {
    const float* hww = &hw[w * 272];
    int b = lane / 12, p = lane % 12;
    float o = sow[816 + p];
#pragma unroll
    for (int kq = 0; kq < 16; ++kq) {
      float4 hv = *(const float4*)&hww[b * 68 + 4 * kq];
      float4 wv = *(const float4*)&sow[p * 68 + 4 * kq];
      o += hv.x * wv.x + hv.y * wv.y + hv.z * wv.z + hv.w * wv.w;
    }
    int oi = (b * NN + n) * 12 + p;
    if (isbf) ((unsigned short*)out)[oi] = f2b(o);
    else      ((float*)out)[oi] = o;
  }
}

extern "C" void kernel_launch(void* const* d_in, const int* in_sizes, int n_in,
                              void* d_out, int out_size, void* d_ws, size_t ws_size,
                              hipStream_t stream) {
  const void* x   = d_in[0];
  const void* ei  = d_in[1];
  const void* ea  = d_in[2];
  const void* czw = d_in[3];
  const void* czb = d_in[4];
  // d_in[5], d_in[6]: conv_r_* — dead (H0 = 0)
  const void* chw = d_in[7];
  const void* chb = d_in[8];
  const void* lzw = d_in[9];
  const void* lzb = d_in[10];
  // d_in[11], d_in[12]: lin_r_* — dead
  const void* lhw = d_in[13];
  const void* lhb = d_in[14];
  const void* att = d_in[15];
  const void* ow  = d_in[16];
  const void* ob  = d_in[17];

  // workspace ~5.4 MB; poison-tolerant (no pre-zero pass needed)
  char* ws = (char*)d_ws;
  float* consts  = (float*)(ws + 256);              // 1992 f32 -> ends 8224
  unsigned long long* degcnt = (unsigned long long*)(ws + 8448);   // 160,000 B compact
  unsigned int* ovf_cnt = (unsigned int*)(ws + 168448);
  int*   ovf_dst = (int*)  (ws + 168704);           // 32768 B
  unsigned int* ovf_pack = (unsigned int*)(ws + 201472);  // 32768 B
  unsigned int* slab     = (unsigned int*)(ws + 234240);  // 5,120,000 B -> 5,354,240

  k_append<<<dim3(EBLK + 1), dim3(256), 0, stream>>>(ei, ea, degcnt, slab,
                                                     ovf_cnt, ovf_dst, ovf_pack,
                                                     consts,
                                                     czw, czb, chw, chb,
                                                     lzw, lzb, lhw, lhb,
                                                     att, ow, ob);
  k_node<<<dim3(NN / 4), dim3(256), 0, stream>>>(x, ei, ea, degcnt, slab,
                                                 ovf_cnt, ovf_dst, ovf_pack,
                                                 consts, d_out);
}

// Round 13
// 240.581 us; speedup vs baseline: 1.0123x; 1.0123x over previous
//
#include <hip/hip_runtime.h>

#define NN 20000
#define EE 320000
#define CAP 64           // slab slots per node (in-degree ~ Poisson(16))
#define SVC 72           // per-wave edge capacity (CAP + ovf slack + self)
#define OVCAP 8192
#define EBLK 313         // edge blocks: ceil(320000/1024)

// consts layout (float offsets)
#define WZ_O 0
#define BZ_O 512
#define WH_O 576
#define BH_O 1088
#define OWT_O 1152       // transposed+padded out weights: [p][68] (k<64 valid)
#define OB_O 1968
#define PR_O 1980
#define NCONST 1992

#define LOG2E  1.4426950408889634f
#define LOG2E2 2.8853900817779268f

__device__ __forceinline__ float b2f(unsigned short h) {
  union { unsigned int u; float f; } v; v.u = ((unsigned int)h) << 16; return v.f;
}
__device__ __forceinline__ unsigned short f2b(float f) {
  union { unsigned int u; float f; } v; v.f = f;
  unsigned int u = v.u;
  unsigned int r = (u + 0x7fffu + ((u >> 16) & 1u)) >> 16;  // RNE
  return (unsigned short)r;
}
__device__ __forceinline__ float ldw(const void* p, int i, int isbf) {
  return isbf ? b2f(((const unsigned short*)p)[i]) : ((const float*)p)[i];
}
__device__ __forceinline__ void upk(unsigned int w, float& x0, float& x1) {
  union { unsigned int u; float f; } lo, hi;
  lo.u = w << 16; hi.u = w & 0xffff0000u;
  x0 = lo.f; x1 = hi.f;
}
__device__ __forceinline__ float degf(unsigned long long dc) {
  return (float)(unsigned int)dc * (1.0f / 1048576.0f);
}

// 1) k_append: blocks 0..EBLK-1 process 4 edges/thread (one packed 64-bit atomic
//    per edge -> slot index in hi32 + fixed-point weighted degree in lo32; degcnt
//    pre-zeroed by a 160 KB memset). Block EBLK (concurrent): fused-weight prep.
//    Dtype detection is block-local (64-lane ballot) -> no cross-block dependency.
__global__ void __launch_bounds__(256) k_append(
    const void* __restrict__ ei, const void* __restrict__ ea,
    unsigned long long* __restrict__ degcnt,
    unsigned int* __restrict__ slab,
    int* __restrict__ ovf_cnt, int* __restrict__ ovf_dst,
    unsigned int* __restrict__ ovf_pack, float* __restrict__ consts,
    const void* czw, const void* czb, const void* chw, const void* chb,
    const void* lzw, const void* lzb, const void* lhw, const void* lhb,
    const void* att, const void* ow, const void* ob) {
  __shared__ int sfl[2];
  const int tid = threadIdx.x;
  if (tid < 64) {
    // edge_attr in (0,1): packed-bf16 words have sign bits 15/31==0; f32 random bit15
    unsigned long long b1 = __ballot((((const unsigned int*)ea)[tid] >> 15) & 1u);
    // edge_index < 20000: int64 arrays have all odd 32-bit words == 0
    unsigned long long b2 = __ballot(((const unsigned int*)ei)[2 * tid + 1] != 0u);
    if (tid == 0) {
      sfl[0] = (b1 == 0ull) ? 1 : 0;   // 1 = floats are bf16
      sfl[1] = (b2 == 0ull) ? 1 : 0;   // 1 = indices are int64
    }
  }
  __syncthreads();
  const int isbf = sfl[0], is64 = sfl[1];

  if (blockIdx.x == EBLK) {
    // ---- weight prep block (concurrent with edge blocks) ----
    // Gate weights pre-scaled for exp2: Wz,bz by log2(e); Wh,bh by 2*log2(e).
    for (int idx = tid; idx < 512; idx += 256) {
      int f = idx >> 6, k = idx & 63;
      float sz = 0.f, sh = 0.f;
      for (int h = 0; h < 64; ++h) {
        sz += ldw(czw, f * 64 + h, isbf) * ldw(lzw, h * 64 + k, isbf);
        sh += ldw(chw, f * 64 + h, isbf) * ldw(lhw, h * 64 + k, isbf);
      }
      consts[WZ_O + idx] = sz * LOG2E; consts[WH_O + idx] = sh * LOG2E2;
    }
    for (int idx = tid; idx < 64; idx += 256) {
      float sz = ldw(lzb, idx, isbf), sh = ldw(lhb, idx, isbf);
      for (int h = 0; h < 64; ++h) {
        sz += ldw(czb, h, isbf) * ldw(lzw, h * 64 + idx, isbf);
        sh += ldw(chb, h, isbf) * ldw(lhw, h * 64 + idx, isbf);
      }
      consts[BZ_O + idx] = sz * LOG2E; consts[BH_O + idx] = sh * LOG2E2;
    }
    for (int idx = tid; idx < 816; idx += 256) {    // out weights [p][k], rows padded to 68
      int p = idx / 68, kk = idx % 68;
      consts[OWT_O + idx] = (kk < 64) ? ldw(ow, kk * 12 + p, isbf) : 0.f;
    }
    if (tid < 12) consts[OB_O + tid] = ldw(ob, tid, isbf);
    if (tid == 0) {
      float a[12]; float m = -1e30f;
      for (int p = 0; p < 12; ++p) { a[p] = ldw(att, p, isbf); m = fmaxf(m, a[p]); }
      float ssum = 0.f;
      for (int p = 0; p < 12; ++p) { a[p] = __expf(a[p] - m); ssum += a[p]; }
      for (int p = 0; p < 12; ++p) consts[PR_O + p] = a[p] / ssum;
    }
    return;
  }

  // ---- edge blocks: 4 edges per thread, independent chains ----
  const int e0 = blockIdx.x * 1024 + tid;
#pragma unroll
  for (int u = 0; u < 4; ++u) {
    int e = e0 + 256 * u;
    if (e >= EE) continue;
    int r, c;
    if (is64) {
      r = (int)((const unsigned int*)ei)[2 * e];
      c = (int)((const unsigned int*)ei)[2 * (EE + e)];
    } else {
      r = ((const int*)ei)[e];
      c = ((const int*)ei)[EE + e];
    }
    unsigned short wb;
    float w;
    if (isbf) { wb = ((const unsigned short*)ea)[e]; w = b2f(wb); }
    else      { w = ((const float*)ea)[e]; wb = f2b(w); }
    unsigned long long pk = (1ull << 32) |
        (unsigned long long)(unsigned int)__float2int_rn(w * 1048576.0f);
    unsigned long long old = atomicAdd(&degcnt[c], pk);
    int pos = (int)(old >> 32);
    unsigned int packed = ((unsigned int)wb << 16) | (unsigned int)r;
    if (pos < CAP) {
      slab[c * CAP + pos] = packed;
    } else {
      int oi = atomicAdd(ovf_cnt, 1);
      if (oi < OVCAP) { ovf_dst[oi] = c; ovf_pack[oi] = packed; }
    }
  }
}

#define ACC8(u, v)                                           \
  { float x0, x1;                                            \
    upk((u).x, x0, x1); a[0] += (v) * x0; a[1] += (v) * x1;  \
    upk((u).y, x0, x1); a[2] += (v) * x0; a[3] += (v) * x1;  \
    upk((u).z, x0, x1); a[4] += (v) * x0; a[5] += (v) * x1;  \
    upk((u).w, x0, x1); a[6] += (v) * x0; a[7] += (v) * x1; }

#define ACCF8(u0, u1, v)                                                       \
  { a[0] += (v) * (u0).x; a[1] += (v) * (u0).y; a[2] += (v) * (u0).z;          \
    a[3] += (v) * (u0).w; a[4] += (v) * (u1).x; a[5] += (v) * (u1).y;          \
    a[6] += (v) * (u1).z; a[7] += (v) * (u1).w; }

// 2) barrier-free wave-per-node: 4 waves/block, each wave owns one node.
__global__ void __launch_bounds__(256) k_node(
    const void* __restrict__ x, const void* __restrict__ ea,
    const unsigned long long* __restrict__ degcnt,
    const unsigned int* __restrict__ slab,
    const int* __restrict__ ovf_cnt, const int* __restrict__ ovf_dst,
    const unsigned int* __restrict__ ovf_pack,
    const float* __restrict__ consts,
    void* __restrict__ out) {
  __shared__ __align__(16) float sow[840];        // owT 816 | ob 12 | pr 12
  __shared__ __align__(16) int2  sv[4 * SVC];     // per-wave edges {soff, v-bits}
  __shared__ __align__(16) float accT[4 * 384];   // per-wave [b][p][f]
  __shared__ __align__(16) float hw[4 * 272];     // per-wave [b][68]
  __shared__ int swcnt[4];
  __shared__ int sfl[1];

  const int tid  = threadIdx.x;
  const int w    = tid >> 6;
  const int lane = tid & 63;
  const int n    = blockIdx.x * 4 + w;

  if (tid < 64) {
    unsigned long long b1 = __ballot((((const unsigned int*)ea)[tid] >> 15) & 1u);
    if (tid == 0) sfl[0] = (b1 == 0ull) ? 1 : 0;
  }
  for (int i = tid; i < 840; i += 256) sow[i] = consts[OWT_O + i];
  float wz[8], wh[8];
#pragma unroll
  for (int f = 0; f < 8; ++f) {
    wz[f] = consts[WZ_O + f * 64 + lane];
    wh[f] = consts[WH_O + f * 64 + lane];
  }
  const float bz = consts[BZ_O + lane], bh = consts[BH_O + lane];
  __syncthreads();   // sow + sfl ready (only block barrier)
  const int isbf = sfl[0];

  float prr[12];
#pragma unroll
  for (int p = 0; p < 12; ++p) prr[p] = sow[828 + p];

  // --- stage this wave's edges into its LDS slab ---
  unsigned long long dcn = degcnt[n];
  int cnt = (int)(dcn >> 32);
  int base = cnt < CAP ? cnt : CAP;
  const float dn = rsqrtf(degf(dcn) + 1.0f);
  int2* svw = &sv[w * SVC];
  if (lane == 0) swcnt[w] = base;
  if (lane < base) {
    unsigned int pk = slab[n * CAP + lane];
    int s = (int)(pk & 0xffffu);
    float v = b2f((unsigned short)(pk >> 16)) * rsqrtf(degf(degcnt[s]) + 1.0f);
    svw[lane] = make_int2(s * 96, __float_as_int(v));
  }
  int m0 = base;
  {
    int ov = ovf_cnt[0];                 // expected 0
    if (ov > 0) {
      if (ov > OVCAP) ov = OVCAP;
      for (int i = lane; i < ov; i += 64) {
        if (ovf_dst[i] == n) {
          int idx = atomicAdd(&swcnt[w], 1);
          if (idx < SVC - 1) {
            unsigned int pk = ovf_pack[i];
            int s = (int)(pk & 0xffffu);
            float v = b2f((unsigned short)(pk >> 16)) *
                      rsqrtf(degf(degcnt[s]) + 1.0f);
            svw[idx] = make_int2(s * 96, __float_as_int(v));
          }
        }
      }
      __builtin_amdgcn_wave_barrier();
      m0 = swcnt[w];
      if (m0 > SVC - 1) m0 = SVC - 1;
    }
  }
  if (lane == 0) svw[m0] = make_int2(n * 96, __float_as_int(dn));  // self loop
  const int m1 = m0 + 1;
  __builtin_amdgcn_wave_barrier();

  // --- gather: lanes 0..47, lane owns 8 payload elems; 2-wide pipelined loads ---
  float a[8];
#pragma unroll
  for (int t = 0; t < 8; ++t) a[t] = 0.f;
  if (lane < 48) {
    const long xbase = (long)(lane / 12) * (NN * 96) + 8 * (lane % 12);
    if (isbf) {
      const unsigned short* xb = (const unsigned short*)x;
      int j = 0;
      for (; j + 1 < m1; j += 2) {
        int2 e0 = svw[j], e1 = svw[j + 1];
        uint4 u0 = *(const uint4*)(xb + xbase + e0.x);
        uint4 u1 = *(const uint4*)(xb + xbase + e1.x);
        float v0 = __int_as_float(e0.y), v1 = __int_as_float(e1.y);
        ACC8(u0, v0); ACC8(u1, v1);
      }
      if (j < m1) {
        int2 e0 = svw[j];
        uint4 u0 = *(const uint4*)(xb + xbase + e0.x);
        float v0 = __int_as_float(e0.y);
        ACC8(u0, v0);
      }
    } else {
      const float* xf = (const float*)x;
      int j = 0;
      for (; j + 1 < m1; j += 2) {
        int2 e0 = svw[j], e1 = svw[j + 1];
        const float4* p0 = (const float4*)(xf + xbase + e0.x);
        const float4* p1 = (const float4*)(xf + xbase + e1.x);
        float4 u00 = p0[0], u01 = p0[1], u10 = p1[0], u11 = p1[1];
        float v0 = __int_as_float(e0.y), v1 = __int_as_float(e1.y);
        ACCF8(u00, u01, v0); ACCF8(u10, u11, v1);
      }
      if (j < m1) {
        int2 e0 = svw[j];
        const float4* p0 = (const float4*)(xf + xbase + e0.x);
        float4 u00 = p0[0], u01 = p0[1];
        float v0 = __int_as_float(e0.y);
        ACCF8(u00, u01, v0);
      }
    }
    // scatter-transpose into accT[b][p][f], scaled by dn
    float* accTw = &accT[w * 384];
    const int bq = (lane / 12) * 96, oc = 8 * (lane % 12);
#pragma unroll
    for (int t = 0; t < 8; ++t) {
      int eib = oc + t;
      int f = eib / 12, p = eib % 12;
      accTw[bq + p * 8 + f] = dn * a[t];
    }
  }
  __builtin_amdgcn_wave_barrier();

  // --- gates: lane = hidden index k; all 48 (b,p) pairs; h accumulated per b ---
  {
    const float* accTw = &accT[w * 384];
    float* hww = &hw[w * 272];
#pragma unroll
    for (int b = 0; b < 4; ++b) {
      float hbl = 0.f;
#pragma unroll
      for (int p = 0; p < 12; ++p) {
        const float4* A = (const float4*)&accTw[b * 96 + p * 8];
        float4 A0 = A[0], A1 = A[1];
        float za = bz + A0.x * wz[0] + A0.y * wz[1] + A0.z * wz[2] + A0.w * wz[3]
                      + A1.x * wz[4] + A1.y * wz[5] + A1.z * wz[6] + A1.w * wz[7];
        float ta = bh + A0.x * wh[0] + A0.y * wh[1] + A0.z * wh[2] + A0.w * wh[3]
                      + A1.x * wh[4] + A1.y * wh[5] + A1.z * wh[6] + A1.w * wh[7];
        // weights pre-scaled by log2e / 2log2e: ea=2^za=e^za_orig, eh=2^ta=e^{2ta_orig}
        // (1 - sigmoid) * tanh = (eh-1) / ((1+ea)(1+eh))
        float ea2 = exp2f(za);
        float eh = exp2f(fminf(ta, 115.0f));
        hbl += prr[p] * (eh - 1.0f) *
               __builtin_amdgcn_rcpf((1.0f + ea2) * (1.0f + eh));
      }
      hww[b * 68 + lane] = fmaxf(hbl, 0.f);   // relu
    }
  }
  __builtin_amdgcn_wave_barrier();

  // --- out projection: lane t<48 -> (b,p); vectorized b128 reads ---
  if (lane < 48) {
    const float* hww = &hw[w * 272];
    int b = lane / 12, p = lane % 12;
    float o = sow[816 + p];
#pragma unroll
    for (int kq = 0; kq < 16; ++kq) {
      float4 hv = *(const float4*)&hww[b * 68 + 4 * kq];
      float4 wv = *(const float4*)&sow[p * 68 + 4 * kq];
      o += hv.x * wv.x + hv.y * wv.y + hv.z * wv.z + hv.w * wv.w;
    }
    int oi = (b * NN + n) * 12 + p;
    if (isbf) ((unsigned short*)out)[oi] = f2b(o);
    else      ((float*)out)[oi] = o;
  }
}

extern "C" void kernel_launch(void* const* d_in, const int* in_sizes, int n_in,
                              void* d_out, int out_size, void* d_ws, size_t ws_size,
                              hipStream_t stream) {
  const void* x   = d_in[0];
  const void* ei  = d_in[1];
  const void* ea  = d_in[2];
  const void* czw = d_in[3];
  const void* czb = d_in[4];
  // d_in[5], d_in[6]: conv_r_* — dead (H0 = 0)
  const void* chw = d_in[7];
  const void* chb = d_in[8];
  const void* lzw = d_in[9];
  const void* lzb = d_in[10];
  // d_in[11], d_in[12]: lin_r_* — dead
  const void* lhw = d_in[13];
  const void* lhb = d_in[14];
  const void* att = d_in[15];
  const void* ow  = d_in[16];
  const void* ob  = d_in[17];

  // workspace ~5.4 MB
  char* ws = (char*)d_ws;
  float* consts  = (float*)(ws + 256);              // 1992 f32 -> ends 8224
  unsigned long long* degcnt = (unsigned long long*)(ws + 8448);   // 160,000 B compact
  int*   ovf_cnt = (int*)  (ws + 168448);           // right after degcnt (one memset)
  int*   ovf_dst = (int*)  (ws + 168704);           // 32768 B
  unsigned int* ovf_pack = (unsigned int*)(ws + 201472);  // 32768 B
  unsigned int* slab     = (unsigned int*)(ws + 234240);  // 5,120,000 B -> 5,354,240

  // zero degcnt + ovf_cnt (160 KB DMA fill)
  hipMemsetAsync(ws + 8448, 0, 160064, stream);
  k_append<<<dim3(EBLK + 1), dim3(256), 0, stream>>>(ei, ea, degcnt, slab,
                                                     ovf_cnt, ovf_dst, ovf_pack,
                                                     consts,
                                                     czw, czb, chw, chb,
                                                     lzw, lzb, lhw, lhb,
                                                     att, ow, ob);
  k_node<<<dim3(NN / 4), dim3(256), 0, stream>>>(x, ea, degcnt, slab,
                                                 ovf_cnt, ovf_dst, ovf_pack,
                                                 consts, d_out);
}

// Round 14
// 230.318 us; speedup vs baseline: 1.0574x; 1.0446x over previous
//
#include <hip/hip_runtime.h>

#define NN 20000
#define EE 320000
#define CAP 64           // slab slots per node (in-degree ~ Poisson(16))
#define SVC 72           // per-wave edge capacity (CAP + ovf slack + self)
#define OVCAP 8192
#define EBLK 313         // edge blocks: ceil(320000/1024)

// consts layout (float offsets)
#define WZ_O 0
#define BZ_O 512
#define WH_O 576
#define BH_O 1088
#define OWT_O 1152       // transposed+padded out weights: [p][68] (k<64 valid)
#define OB_O 1968
#define PR_O 1980
#define NCONST 1992

__device__ __forceinline__ float b2f(unsigned short h) {
  union { unsigned int u; float f; } v; v.u = ((unsigned int)h) << 16; return v.f;
}
__device__ __forceinline__ unsigned short f2b(float f) {
  union { unsigned int u; float f; } v; v.f = f;
  unsigned int u = v.u;
  unsigned int r = (u + 0x7fffu + ((u >> 16) & 1u)) >> 16;  // RNE
  return (unsigned short)r;
}
__device__ __forceinline__ float ldw(const void* p, int i, int isbf) {
  return isbf ? b2f(((const unsigned short*)p)[i]) : ((const float*)p)[i];
}
__device__ __forceinline__ void upk(unsigned int w, float& x0, float& x1) {
  union { unsigned int u; float f; } lo, hi;
  lo.u = w << 16; hi.u = w & 0xffff0000u;
  x0 = lo.f; x1 = hi.f;
}
__device__ __forceinline__ float degf(unsigned long long dc) {
  return (float)(unsigned int)dc * (1.0f / 1048576.0f);
}

// 1) k_append: blocks 0..EBLK-1 process 4 edges/thread (one packed 64-bit atomic
//    per edge -> slot index in hi32 + fixed-point weighted degree in lo32; degcnt
//    pre-zeroed by a 160 KB memset). Block EBLK (concurrent): fused-weight prep.
//    Dtype detection is block-local (64-lane ballot) -> no cross-block dependency.
__global__ void __launch_bounds__(256) k_append(
    const void* __restrict__ ei, const void* __restrict__ ea,
    unsigned long long* __restrict__ degcnt,
    unsigned int* __restrict__ slab,
    int* __restrict__ ovf_cnt, int* __restrict__ ovf_dst,
    unsigned int* __restrict__ ovf_pack, float* __restrict__ consts,
    const void* czw, const void* czb, const void* chw, const void* chb,
    const void* lzw, const void* lzb, const void* lhw, const void* lhb,
    const void* att, const void* ow, const void* ob) {
  __shared__ int sfl[2];
  const int tid = threadIdx.x;
  if (tid < 64) {
    // edge_attr in (0,1): packed-bf16 words have sign bits 15/31==0; f32 random bit15
    unsigned long long b1 = __ballot((((const unsigned int*)ea)[tid] >> 15) & 1u);
    // edge_index < 20000: int64 arrays have all odd 32-bit words == 0
    unsigned long long b2 = __ballot(((const unsigned int*)ei)[2 * tid + 1] != 0u);
    if (tid == 0) {
      sfl[0] = (b1 == 0ull) ? 1 : 0;   // 1 = floats are bf16
      sfl[1] = (b2 == 0ull) ? 1 : 0;   // 1 = indices are int64
    }
  }
  __syncthreads();
  const int isbf = sfl[0], is64 = sfl[1];

  if (blockIdx.x == EBLK) {
    // ---- weight prep block (concurrent with edge blocks) ----
    for (int idx = tid; idx < 512; idx += 256) {
      int f = idx >> 6, k = idx & 63;
      float sz = 0.f, sh = 0.f;
      for (int h = 0; h < 64; ++h) {
        sz += ldw(czw, f * 64 + h, isbf) * ldw(lzw, h * 64 + k, isbf);
        sh += ldw(chw, f * 64 + h, isbf) * ldw(lhw, h * 64 + k, isbf);
      }
      consts[WZ_O + idx] = sz; consts[WH_O + idx] = sh;
    }
    for (int idx = tid; idx < 64; idx += 256) {
      float sz = ldw(lzb, idx, isbf), sh = ldw(lhb, idx, isbf);
      for (int h = 0; h < 64; ++h) {
        sz += ldw(czb, h, isbf) * ldw(lzw, h * 64 + idx, isbf);
        sh += ldw(chb, h, isbf) * ldw(lhw, h * 64 + idx, isbf);
      }
      consts[BZ_O + idx] = sz; consts[BH_O + idx] = sh;
    }
    for (int idx = tid; idx < 816; idx += 256) {    // out weights [p][k], rows padded to 68
      int p = idx / 68, kk = idx % 68;
      consts[OWT_O + idx] = (kk < 64) ? ldw(ow, kk * 12 + p, isbf) : 0.f;
    }
    if (tid < 12) consts[OB_O + tid] = ldw(ob, tid, isbf);
    if (tid == 0) {
      float a[12]; float m = -1e30f;
      for (int p = 0; p < 12; ++p) { a[p] = ldw(att, p, isbf); m = fmaxf(m, a[p]); }
      float ssum = 0.f;
      for (int p = 0; p < 12; ++p) { a[p] = __expf(a[p] - m); ssum += a[p]; }
      for (int p = 0; p < 12; ++p) consts[PR_O + p] = a[p] / ssum;
    }
    return;
  }

  // ---- edge blocks: 4 edges per thread, independent chains ----
  const int e0 = blockIdx.x * 1024 + tid;
#pragma unroll
  for (int u = 0; u < 4; ++u) {
    int e = e0 + 256 * u;
    if (e >= EE) continue;
    int r, c;
    if (is64) {
      r = (int)((const unsigned int*)ei)[2 * e];
      c = (int)((const unsigned int*)ei)[2 * (EE + e)];
    } else {
      r = ((const int*)ei)[e];
      c = ((const int*)ei)[EE + e];
    }
    unsigned short wb;
    float w;
    if (isbf) { wb = ((const unsigned short*)ea)[e]; w = b2f(wb); }
    else      { w = ((const float*)ea)[e]; wb = f2b(w); }
    unsigned long long pk = (1ull << 32) |
        (unsigned long long)(unsigned int)__float2int_rn(w * 1048576.0f);
    unsigned long long old = atomicAdd(&degcnt[c], pk);
    int pos = (int)(old >> 32);
    unsigned int packed = ((unsigned int)wb << 16) | (unsigned int)r;
    if (pos < CAP) {
      slab[c * CAP + pos] = packed;
    } else {
      int oi = atomicAdd(ovf_cnt, 1);
      if (oi < OVCAP) { ovf_dst[oi] = c; ovf_pack[oi] = packed; }
    }
  }
}

#define ACC8(u, v)                                           \
  { float x0, x1;                                            \
    upk((u).x, x0, x1); a[0] += (v) * x0; a[1] += (v) * x1;  \
    upk((u).y, x0, x1); a[2] += (v) * x0; a[3] += (v) * x1;  \
    upk((u).z, x0, x1); a[4] += (v) * x0; a[5] += (v) * x1;  \
    upk((u).w, x0, x1); a[6] += (v) * x0; a[7] += (v) * x1; }

#define ACCF8(u0, u1, v)                                                       \
  { a[0] += (v) * (u0).x; a[1] += (v) * (u0).y; a[2] += (v) * (u0).z;          \
    a[3] += (v) * (u0).w; a[4] += (v) * (u1).x; a[5] += (v) * (u1).y;          \
    a[6] += (v) * (u1).z; a[7] += (v) * (u1).w; }

// 2) barrier-free wave-per-node (R12 structure, 48 VGPR / 86 µs verified):
//    4 waves/block, each wave owns one node end-to-end.
__global__ void __launch_bounds__(256) k_node(
    const void* __restrict__ x, const void* __restrict__ ea,
    const unsigned long long* __restrict__ degcnt,
    const unsigned int* __restrict__ slab,
    const int* __restrict__ ovf_cnt, const int* __restrict__ ovf_dst,
    const unsigned int* __restrict__ ovf_pack,
    const float* __restrict__ consts,
    void* __restrict__ out) {
  __shared__ __align__(16) float sow[840];        // owT 816 | ob 12 | pr 12
  __shared__ __align__(16) int2  sv[4 * SVC];     // per-wave edges {soff, v-bits}
  __shared__ __align__(16) float accT[4 * 384];   // per-wave [b][p][f]
  __shared__ __align__(16) float hw[4 * 272];     // per-wave [b][68]
  __shared__ int swcnt[4];
  __shared__ int sfl[1];

  const int tid  = threadIdx.x;
  const int w    = tid >> 6;
  const int lane = tid & 63;
  const int n    = blockIdx.x * 4 + w;

  if (tid < 64) {
    unsigned long long b1 = __ballot((((const unsigned int*)ea)[tid] >> 15) & 1u);
    if (tid == 0) sfl[0] = (b1 == 0ull) ? 1 : 0;
  }
  for (int i = tid; i < 840; i += 256) sow[i] = consts[OWT_O + i];
  float wz[8], wh[8];
#pragma unroll
  for (int f = 0; f < 8; ++f) {
    wz[f] = consts[WZ_O + f * 64 + lane];
    wh[f] = consts[WH_O + f * 64 + lane];
  }
  const float bz = consts[BZ_O + lane], bh = consts[BH_O + lane];
  __syncthreads();   // sow + sfl ready (only block barrier)
  const int isbf = sfl[0];

  // --- stage this wave's edges into its LDS slab ---
  unsigned long long dcn = degcnt[n];
  int cnt = (int)(dcn >> 32);
  int base = cnt < CAP ? cnt : CAP;
  const float dn = rsqrtf(degf(dcn) + 1.0f);
  int2* svw = &sv[w * SVC];
  if (lane == 0) swcnt[w] = base;
  if (lane < base) {
    unsigned int pk = slab[n * CAP + lane];
    int s = (int)(pk & 0xffffu);
    float v = b2f((unsigned short)(pk >> 16)) * rsqrtf(degf(degcnt[s]) + 1.0f);
    svw[lane] = make_int2(s * 96, __float_as_int(v));
  }
  int m0 = base;
  {
    int ov = ovf_cnt[0];                 // expected 0
    if (ov > 0) {
      if (ov > OVCAP) ov = OVCAP;
      for (int i = lane; i < ov; i += 64) {
        if (ovf_dst[i] == n) {
          int idx = atomicAdd(&swcnt[w], 1);
          if (idx < SVC - 1) {
            unsigned int pk = ovf_pack[i];
            int s = (int)(pk & 0xffffu);
            float v = b2f((unsigned short)(pk >> 16)) *
                      rsqrtf(degf(degcnt[s]) + 1.0f);
            svw[idx] = make_int2(s * 96, __float_as_int(v));
          }
        }
      }
      __builtin_amdgcn_wave_barrier();
      m0 = swcnt[w];
      if (m0 > SVC - 1) m0 = SVC - 1;
    }
  }
  if (lane == 0) svw[m0] = make_int2(n * 96, __float_as_int(dn));  // self loop
  const int m1 = m0 + 1;
  __builtin_amdgcn_wave_barrier();

  // --- gather: lanes 0..47, lane owns 8 payload elems; 2-wide pipelined loads ---
  float a[8];
#pragma unroll
  for (int t = 0; t < 8; ++t) a[t] = 0.f;
  if (lane < 48) {
    const long xbase = (long)(lane / 12) * (NN * 96) + 8 * (lane % 12);
    if (isbf) {
      const unsigned short* xb = (const unsigned short*)x;
      int j = 0;
      for (; j + 1 < m1; j += 2) {
        int2 e0 = svw[j], e1 = svw[j + 1];
        uint4 u0 = *(const uint4*)(xb + xbase + e0.x);
        uint4 u1 = *(const uint4*)(xb + xbase + e1.x);
        float v0 = __int_as_float(e0.y), v1 = __int_as_float(e1.y);
        ACC8(u0, v0); ACC8(u1, v1);
      }
      if (j < m1) {
        int2 e0 = svw[j];
        uint4 u0 = *(const uint4*)(xb + xbase + e0.x);
        float v0 = __int_as_float(e0.y);
        ACC8(u0, v0);
      }
    } else {
      const float* xf = (const float*)x;
      int j = 0;
      for (; j + 1 < m1; j += 2) {
        int2 e0 = svw[j], e1 = svw[j + 1];
        const float4* p0 = (const float4*)(xf + xbase + e0.x);
        const float4* p1 = (const float4*)(xf + xbase + e1.x);
        float4 u00 = p0[0], u01 = p0[1], u10 = p1[0], u11 = p1[1];
        float v0 = __int_as_float(e0.y), v1 = __int_as_float(e1.y);
        ACCF8(u00, u01, v0); ACCF8(u10, u11, v1);
      }
      if (j < m1) {
        int2 e0 = svw[j];
        const float4* p0 = (const float4*)(xf + xbase + e0.x);
        float4 u00 = p0[0], u01 = p0[1];
        float v0 = __int_as_float(e0.y);
        ACCF8(u00, u01, v0);
      }
    }
    // scatter-transpose into accT[b][p][f], scaled by dn
    float* accTw = &accT[w * 384];
    const int bq = (lane / 12) * 96, oc = 8 * (lane % 12);
#pragma unroll
    for (int t = 0; t < 8; ++t) {
      int eib = oc + t;
      int f = eib / 12, p = eib % 12;
      accTw[bq + p * 8 + f] = dn * a[t];
    }
  }
  __builtin_amdgcn_wave_barrier();

  // --- gates: lane = hidden index k; all 48 (b,p) pairs; h accumulated per b ---
  {
    const float* accTw = &accT[w * 384];
    float* hww = &hw[w * 272];
#pragma unroll
    for (int b = 0; b < 4; ++b) {
      float hbl = 0.f;
#pragma unroll
      for (int p = 0; p < 12; ++p) {
        const float4* A = (const float4*)&accTw[b * 96 + p * 8];
        float4 A0 = A[0], A1 = A[1];
        float za = bz + A0.x * wz[0] + A0.y * wz[1] + A0.z * wz[2] + A0.w * wz[3]
                      + A1.x * wz[4] + A1.y * wz[5] + A1.z * wz[6] + A1.w * wz[7];
        float ta = bh + A0.x * wh[0] + A0.y * wh[1] + A0.z * wh[2] + A0.w * wh[3]
                      + A1.x * wh[4] + A1.y * wh[5] + A1.z * wh[6] + A1.w * wh[7];
        // (1 - sigmoid(za)) * tanh(ta) = (eh-1)/((1+ea)(1+eh)), ea=e^za, eh=e^{2ta}
        float ea2 = __expf(za);
        float eh = __expf(2.0f * fminf(ta, 40.0f));
        hbl += sow[828 + p] * (eh - 1.0f) *
               __builtin_amdgcn_rcpf((1.0f + ea2) * (1.0f + eh));
      }
      hww[b * 68 + lane] = fmaxf(hbl, 0.f);   // relu
    }
  }
  __builtin_amdgcn_wave_barrier();

  // --- out projection: lane t<48 -> (b,p); vectorized b128 reads ---
  if (lane < 48) {
    const float* hww = &hw[w * 272];
    int b = lane / 12, p = lane % 12;
    float o = sow[816 + p];
#pragma unroll
    for (int kq = 0; kq < 16; ++kq) {
      float4 hv = *(const float4*)&hww[b * 68 + 4 * kq];
      float4 wv = *(const float4*)&sow[p * 68 + 4 * kq];
      o += hv.x * wv.x + hv.y * wv.y + hv.z * wv.z + hv.w * wv.w;
    }
    int oi = (b * NN + n) * 12 + p;
    if (isbf) ((unsigned short*)out)[oi] = f2b(o);
    else      ((float*)out)[oi] = o;
  }
}

extern "C" void kernel_launch(void* const* d_in, const int* in_sizes, int n_in,
                              void* d_out, int out_size, void* d_ws, size_t ws_size,
                              hipStream_t stream) {
  const void* x   = d_in[0];
  const void* ei  = d_in[1];
  const void* ea  = d_in[2];
  const void* czw = d_in[3];
  const void* czb = d_in[4];
  // d_in[5], d_in[6]: conv_r_* — dead (H0 = 0)
  const void* chw = d_in[7];
  const void* chb = d_in[8];
  const void* lzw = d_in[9];
  const void* lzb = d_in[10];
  // d_in[11], d_in[12]: lin_r_* — dead
  const void* lhw = d_in[13];
  const void* lhb = d_in[14];
  const void* att = d_in[15];
  const void* ow  = d_in[16];
  const void* ob  = d_in[17];

  // workspace ~5.4 MB
  char* ws = (char*)d_ws;
  float* consts  = (float*)(ws + 256);              // 1992 f32 -> ends 8224
  unsigned long long* degcnt = (unsigned long long*)(ws + 8448);   // 160,000 B compact
  int*   ovf_cnt = (int*)  (ws + 168448);           // right after degcnt (one memset)
  int*   ovf_dst = (int*)  (ws + 168704);           // 32768 B
  unsigned int* ovf_pack = (unsigned int*)(ws + 201472);  // 32768 B
  unsigned int* slab     = (unsigned int*)(ws + 234240);  // 5,120,000 B -> 5,354,240

  // zero degcnt + ovf_cnt (160 KB DMA fill)
  hipMemsetAsync(ws + 8448, 0, 160064, stream);
  k_append<<<dim3(EBLK + 1), dim3(256), 0, stream>>>(ei, ea, degcnt, slab,
                                                     ovf_cnt, ovf_dst, ovf_pack,
                                                     consts,
                                                     czw, czb, chw, chb,
                                                     lzw, lzb, lhw, lhb,
                                                     att, ow, ob);
  k_node<<<dim3(NN / 4), dim3(256), 0, stream>>>(x, ea, degcnt, slab,
                                                 ovf_cnt, ovf_dst, ovf_pack,
                                                 consts, d_out);
}